// Round 6
// baseline (13566.856 us; speedup 1.0000x reference)
//
#include <hip/hip_runtime.h>
#include <hip/hip_bf16.h>
#include <stdint.h>

// Layouts (uint4 = 128 bits of packed sign data):
//   ap  : [32 chunks][8192 rows] uint4   activations, chunk-major
//   wp  : [3][32][4096] uint4            hidden weights
//   wpo : [10][32] uint4                 output weights, row-major

// ---------------------------------------------------------------------------
// Pack f32 -> sign bits, 4 elements per thread (4 coalesced sweeps + ballots),
// chunk-major output. For x: binarize(2v-1) >= 0  <=>  v >= 0.5 (exact).
// ---------------------------------------------------------------------------
__global__ __launch_bounds__(256) void pack_ksign_kernel(
    const float* __restrict__ src, uint32_t* __restrict__ dst,
    float thresh, int rbits)
{
    const int t    = threadIdx.x;
    const int lane = t & 63;
    const int gw   = blockIdx.x * 4 + (t >> 6);     // global wave id
    const size_t base = (size_t)gw * 256;           // 256 elems per wave, same row
    const int gr = gw >> 4;                         // global row (4096 elems/row)
    const int l  = gr >> rbits;                     // matrix index
    const int r  = gr & ((1 << rbits) - 1);         // row within matrix
    const int w0 = (gw & 15) * 8;                   // first kword of this span
#pragma unroll
    for (int j = 0; j < 4; ++j) {
        float v = src[base + j * 64 + lane];
        unsigned long long m = __ballot(v >= thresh);
        if (lane == 0) {
            int w = w0 + 2 * j;                     // even kword
            size_t idx = ((size_t)l << (rbits + 7))
                       + (((size_t)(w >> 2) << rbits) + (size_t)r) * 4
                       + (size_t)(w & 3);
            *(uint2*)(dst + idx) = make_uint2((uint32_t)m, (uint32_t)(m >> 32));
        }
    }
}

// Row-major pack for Wout [10][4096] -> [10][128] words
__global__ __launch_bounds__(256) void pack_rm_kernel(const float* __restrict__ src,
                                                      uint32_t* __restrict__ dst) {
    int tid = blockIdx.x * 256 + threadIdx.x;
    bool pred = src[tid] >= 0.0f;
    unsigned long long m = __ballot(pred);
    if ((threadIdx.x & 63) == 0)
        *(uint2*)(dst + (tid >> 5)) = make_uint2((uint32_t)m, (uint32_t)(m >> 32));
}

__global__ __launch_bounds__(256) void rsqrt_kernel(const float* __restrict__ var,
                                                    float* __restrict__ rs) {
    int tid = blockIdx.x * 256 + threadIdx.x;   // 3*4096 exact
    rs[tid] = 1.0f / sqrtf(var[tid] + 1e-5f);
}

// ---------------------------------------------------------------------------
// Binary GEMM: C[b][o] = 4096 - 2*popc(A[b]^W[o]); fused BN + binarize + pack.
// Block 64x64, 256 threads, 4x4 per thread, K-step = 4 chunks (512 bits),
// 8 iters, double-buffered LDS, 1 barrier/iter.
// LDS layout transposed-within-tile: row (4q + r) lives at slot (r*16 + q)
//   -> A reads: 4 distinct banks, broadcast, conflict-free
//   -> B reads: 16 consecutive slots, minimum bank cycles, conflict-free
//   -> staging writes bank-balanced
// ---------------------------------------------------------------------------
__global__ __launch_bounds__(256, 4) void bgemm_kernel(
    const uint32_t* __restrict__ ap,     // [32][8192] uint4
    const uint32_t* __restrict__ wp,     // [32][4096] uint4
    const float* __restrict__ mean, const float* __restrict__ rsq,
    const float* __restrict__ gamma, const float* __restrict__ beta,
    uint32_t* __restrict__ apOut)        // [32][8192][4] uint32
{
    __shared__ uint4 As[2][4][64];
    __shared__ uint4 Bs[2][4][64];

    const int t  = threadIdx.x;
    const int tx = t & 15;
    const int ty = t >> 4;
    const int bx = blockIdx.x;      // 0..63   (N/64)
    const int by = blockIdx.y;      // 0..127  (M/64)

    // staging: wave w stages chunk w; lane sl loads row sl (coalesced),
    // writes transposed slot.
    const int sc = t >> 6;
    const int sl = t & 63;
    const uint4* gA = (const uint4*)ap + (size_t)sc * 8192 + (size_t)by * 64 + sl;
    const uint4* gB = (const uint4*)wp + (size_t)sc * 4096 + (size_t)bx * 64 + sl;
    const int slot = (sl & 3) * 16 + (sl >> 2);
    uint4* sA = &As[0][sc][slot];
    uint4* sB = &Bs[0][sc][slot];

    sA[0] = gA[0];
    sB[0] = gB[0];

    int cnt[4][4];
#pragma unroll
    for (int r = 0; r < 4; ++r)
#pragma unroll
        for (int j = 0; j < 4; ++j) cnt[r][j] = 0;

    __syncthreads();

#pragma unroll 2
    for (int k = 0; k < 8; ++k) {
        const int buf = k & 1;
        uint4 rA, rB;
        if (k < 7) {
            rA = gA[(size_t)(k + 1) * 32768];   // 4 chunks * 8192
            rB = gB[(size_t)(k + 1) * 16384];   // 4 chunks * 4096
        }

#pragma unroll
        for (int c = 0; c < 4; ++c) {
            uint4 a[4], b[4];
#pragma unroll
            for (int r = 0; r < 4; ++r) a[r] = As[buf][c][r * 16 + ty];
#pragma unroll
            for (int j = 0; j < 4; ++j) b[j] = Bs[buf][c][j * 16 + tx];
#pragma unroll
            for (int r = 0; r < 4; ++r)
#pragma unroll
                for (int j = 0; j < 4; ++j) {
                    cnt[r][j] += __popc(a[r].x ^ b[j].x) + __popc(a[r].y ^ b[j].y)
                               + __popc(a[r].z ^ b[j].z) + __popc(a[r].w ^ b[j].w);
                }
        }

        if (k < 7) {
            sA[(buf ^ 1) * 256] = rA;
            sB[(buf ^ 1) * 256] = rB;
        }
        __syncthreads();
    }

    // Epilogue: BN (left-assoc, no FMA contraction) + binarize + bit-pack.
    {
#pragma clang fp contract(off)
        const int col0 = bx * 64 + tx * 4;
        const float4 mn = *(const float4*)(mean + col0);
        const float4 rv = *(const float4*)(rsq + col0);
        const float4 gm = *(const float4*)(gamma + col0);
        const float4 bt = *(const float4*)(beta + col0);

        const int row0 = by * 64 + ty * 4;
        const int kw   = bx * 2 + (tx >> 3);     // global kword this group builds
        const int chnk = kw >> 2;
        const int pos  = kw & 3;
        const int sh   = (tx & 7) * 4;

#pragma unroll
        for (int r = 0; r < 4; ++r) {
            uint32_t bits = 0;
            float d, tt, y;
            d = (float)(4096 - 2 * cnt[r][0]); tt = (d - mn.x) * rv.x; y = tt * gm.x + bt.x;
            bits |= (y >= 0.0f) ? 1u : 0u;
            d = (float)(4096 - 2 * cnt[r][1]); tt = (d - mn.y) * rv.y; y = tt * gm.y + bt.y;
            bits |= (y >= 0.0f) ? 2u : 0u;
            d = (float)(4096 - 2 * cnt[r][2]); tt = (d - mn.z) * rv.z; y = tt * gm.z + bt.z;
            bits |= (y >= 0.0f) ? 4u : 0u;
            d = (float)(4096 - 2 * cnt[r][3]); tt = (d - mn.w) * rv.w; y = tt * gm.w + bt.w;
            bits |= (y >= 0.0f) ? 8u : 0u;

            uint32_t v = bits << sh;
            v |= __shfl_xor(v, 1);
            v |= __shfl_xor(v, 2);
            v |= __shfl_xor(v, 4);
            if ((tx & 7) == 0)
                apOut[((size_t)chnk * 8192 + (size_t)(row0 + r)) * 4 + pos] = v;
        }
    }
}

// ---------------------------------------------------------------------------
// Final 8192x10x4096 binary GEMM + TensorNorm.
// ---------------------------------------------------------------------------
__global__ __launch_bounds__(256) void final_kernel(
    const uint32_t* __restrict__ ap, const uint32_t* __restrict__ wpo,
    const float* __restrict__ tn_m, const float* __restrict__ tn_v,
    const float* __restrict__ tn_w, const float* __restrict__ tn_b,
    float* __restrict__ out)
{
#pragma clang fp contract(off)
    __shared__ uint4 wsh[10][32];
    for (int i = threadIdx.x; i < 320; i += 256)
        ((uint4*)wsh)[i] = ((const uint4*)wpo)[i];
    __syncthreads();

    const int b = blockIdx.x * 256 + threadIdx.x;   // 8192 exact
    const uint4* pa = (const uint4*)ap + b;
    int cnt[10];
#pragma unroll
    for (int o = 0; o < 10; ++o) cnt[o] = 0;

    for (int k = 0; k < 32; ++k) {
        uint4 A = pa[(size_t)k * 8192];
#pragma unroll
        for (int o = 0; o < 10; ++o) {
            uint4 B = wsh[o][k];
            cnt[o] += __popc(A.x ^ B.x) + __popc(A.y ^ B.y)
                    + __popc(A.z ^ B.z) + __popc(A.w ^ B.w);
        }
    }

    const float m  = tn_m[0];
    const float r  = 1.0f / sqrtf(tn_v[0] + 1e-4f);
    const float w  = tn_w[0];
    const float bb = tn_b[0];
#pragma unroll
    for (int o = 0; o < 10; ++o) {
        float d = (float)(4096 - 2 * cnt[o]);
        float t = (d - m) * r;
        out[b * 10 + o] = t * w + bb;
    }
}

// ---------------------------------------------------------------------------
extern "C" void kernel_launch(void* const* d_in, const int* in_sizes, int n_in,
                              void* d_out, int out_size, void* d_ws, size_t ws_size,
                              hipStream_t stream) {
    const float* x     = (const float*)d_in[0];
    const float* W     = (const float*)d_in[1];
    const float* Wout  = (const float*)d_in[2];
    const float* gamma = (const float*)d_in[3];
    const float* beta  = (const float*)d_in[4];
    const float* mean  = (const float*)d_in[5];
    const float* var   = (const float*)d_in[6];
    const float* tn_w  = (const float*)d_in[7];
    const float* tn_b  = (const float*)d_in[8];
    const float* tn_m  = (const float*)d_in[9];
    const float* tn_v  = (const float*)d_in[10];
    float* out = (float*)d_out;

    uint8_t* ws = (uint8_t*)d_ws;
    uint32_t* ap0 = (uint32_t*)(ws);                      // 4 MB [32][8192][4]
    uint32_t* ap1 = (uint32_t*)(ws + (4u << 20));         // 4 MB
    uint32_t* wp  = (uint32_t*)(ws + (8u << 20));         // 6 MB [3][32][4096][4]
    uint32_t* wpo = (uint32_t*)(ws + (14u << 20));        // 5 KB [10][128]
    float*    rs  = (float*)   (ws + (14u << 20) + 8192); // 48 KB [3][4096]

    // pack input: 33,554,432 elems / 1024 per block
    pack_ksign_kernel<<<32768, 256, 0, stream>>>(x, ap0, 0.5f, 13);
    // pack hidden weights: 50,331,648 elems / 1024 per block
    pack_ksign_kernel<<<49152, 256, 0, stream>>>(W, wp, 0.0f, 12);
    pack_rm_kernel<<<160, 256, 0, stream>>>(Wout, wpo);
    rsqrt_kernel<<<48, 256, 0, stream>>>(var, rs);

    dim3 grid(64, 128);   // (N/64, M/64)
    bgemm_kernel<<<grid, 256, 0, stream>>>(ap0, wp,            mean,        rs,
                                           gamma,        beta,        ap1);
    bgemm_kernel<<<grid, 256, 0, stream>>>(ap1, wp + (1u<<19), mean + 4096, rs + 4096,
                                           gamma + 4096, beta + 4096, ap0);
    bgemm_kernel<<<grid, 256, 0, stream>>>(ap0, wp + (2u<<19), mean + 8192, rs + 8192,
                                           gamma + 8192, beta + 8192, ap1);

    final_kernel<<<32, 256, 0, stream>>>(ap1, wpo, tn_m, tn_v, tn_w, tn_b, out);
}

// Round 7
// 7786.633 us; speedup vs baseline: 1.7423x; 1.7423x over previous
//
#include <hip/hip_runtime.h>
#include <hip/hip_bf16.h>
#include <stdint.h>

// Layouts (uint4 = 128 bits of packed sign data):
//   ap  : [32 chunks][8192 rows] uint4   activations, chunk-major
//   wp  : [3][32][4096] uint4            hidden weights
//   wpo : [10][32] uint4                 output weights, row-major

// ---------------------------------------------------------------------------
// Pack f32 -> sign bits, 4 elements per thread, chunk-major output.
// For x: binarize(2v-1) >= 0  <=>  v >= 0.5 (exact).
// ---------------------------------------------------------------------------
__global__ __launch_bounds__(256) void pack_ksign_kernel(
    const float* __restrict__ src, uint32_t* __restrict__ dst,
    float thresh, int rbits)
{
    const int t    = threadIdx.x;
    const int lane = t & 63;
    const int gw   = blockIdx.x * 4 + (t >> 6);     // global wave id
    const size_t base = (size_t)gw * 256;           // 256 elems per wave, same row
    const int gr = gw >> 4;                         // global row (4096 elems/row)
    const int l  = gr >> rbits;                     // matrix index
    const int r  = gr & ((1 << rbits) - 1);         // row within matrix
    const int w0 = (gw & 15) * 8;                   // first kword of this span
#pragma unroll
    for (int j = 0; j < 4; ++j) {
        float v = src[base + j * 64 + lane];
        unsigned long long m = __ballot(v >= thresh);
        if (lane == 0) {
            int w = w0 + 2 * j;                     // even kword
            size_t idx = ((size_t)l << (rbits + 7))
                       + (((size_t)(w >> 2) << rbits) + (size_t)r) * 4
                       + (size_t)(w & 3);
            *(uint2*)(dst + idx) = make_uint2((uint32_t)m, (uint32_t)(m >> 32));
        }
    }
}

// Row-major pack for Wout [10][4096] -> [10][128] words
__global__ __launch_bounds__(256) void pack_rm_kernel(const float* __restrict__ src,
                                                      uint32_t* __restrict__ dst) {
    int tid = blockIdx.x * 256 + threadIdx.x;
    bool pred = src[tid] >= 0.0f;
    unsigned long long m = __ballot(pred);
    if ((threadIdx.x & 63) == 0)
        *(uint2*)(dst + (tid >> 5)) = make_uint2((uint32_t)m, (uint32_t)(m >> 32));
}

__global__ __launch_bounds__(256) void rsqrt_kernel(const float* __restrict__ var,
                                                    float* __restrict__ rs) {
    int tid = blockIdx.x * 256 + threadIdx.x;   // 3*4096 exact
    rs[tid] = 1.0f / sqrtf(var[tid] + 1e-5f);
}

// ---------------------------------------------------------------------------
// Binary GEMM: C[b][o] = 4096 - 2*popc(A[b]^W[o]); fused BN + binarize + pack.
// Block 64x64, 256 threads, 4x4 per thread, K-step = 4 chunks (512 bits),
// 8 iters, double-buffered LDS, 1 barrier/iter.
// ALL per-thread state in named scalars (no arrays -> no scratch, rule #20).
// LDS layout transposed-within-tile: row (4q + r) lives at slot (r*16 + q).
// ---------------------------------------------------------------------------
#define XP(C, A, B)                                                          \
    C += __popc((A).x ^ (B).x) + __popc((A).y ^ (B).y) +                     \
         __popc((A).z ^ (B).z) + __popc((A).w ^ (B).w)

// one k-chunk: load 4 A-fragments + 4 B-fragments, 16 accumulate ops
#define CSTEP(cc)                                                            \
    {                                                                        \
        uint4 a0 = As[buf][cc][ 0 + ty], a1 = As[buf][cc][16 + ty];          \
        uint4 a2 = As[buf][cc][32 + ty], a3 = As[buf][cc][48 + ty];          \
        uint4 b0 = Bs[buf][cc][ 0 + tx], b1 = Bs[buf][cc][16 + tx];          \
        uint4 b2 = Bs[buf][cc][32 + tx], b3 = Bs[buf][cc][48 + tx];          \
        XP(c00, a0, b0); XP(c01, a0, b1); XP(c02, a0, b2); XP(c03, a0, b3);  \
        XP(c10, a1, b0); XP(c11, a1, b1); XP(c12, a1, b2); XP(c13, a1, b3);  \
        XP(c20, a2, b0); XP(c21, a2, b1); XP(c22, a2, b2); XP(c23, a2, b3);  \
        XP(c30, a3, b0); XP(c31, a3, b1); XP(c32, a3, b2); XP(c33, a3, b3);  \
    }

// BN + binarize + pack one output row (4 cols) and write if leader lane
#define EPIROW(cr0, cr1, cr2, cr3, rr)                                       \
    {                                                                        \
        uint32_t bits = 0;                                                   \
        float d, tt, y;                                                      \
        d = (float)(4096 - 2 * (cr0)); tt = (d - mn.x) * rv.x;               \
        y = tt * gm.x + bt.x; bits |= (y >= 0.0f) ? 1u : 0u;                 \
        d = (float)(4096 - 2 * (cr1)); tt = (d - mn.y) * rv.y;               \
        y = tt * gm.y + bt.y; bits |= (y >= 0.0f) ? 2u : 0u;                 \
        d = (float)(4096 - 2 * (cr2)); tt = (d - mn.z) * rv.z;               \
        y = tt * gm.z + bt.z; bits |= (y >= 0.0f) ? 4u : 0u;                 \
        d = (float)(4096 - 2 * (cr3)); tt = (d - mn.w) * rv.w;               \
        y = tt * gm.w + bt.w; bits |= (y >= 0.0f) ? 8u : 0u;                 \
        uint32_t v = bits << sh;                                             \
        v |= __shfl_xor(v, 1);                                               \
        v |= __shfl_xor(v, 2);                                               \
        v |= __shfl_xor(v, 4);                                               \
        if ((tx & 7) == 0)                                                   \
            apOut[((size_t)chnk * 8192 + (size_t)(row0 + (rr))) * 4 + pos] = v; \
    }

__global__ __launch_bounds__(256, 4) void bgemm_kernel(
    const uint32_t* __restrict__ ap,     // [32][8192] uint4
    const uint32_t* __restrict__ wp,     // [32][4096] uint4
    const float* __restrict__ mean, const float* __restrict__ rsq,
    const float* __restrict__ gamma, const float* __restrict__ beta,
    uint32_t* __restrict__ apOut)        // [32][8192][4] uint32
{
    __shared__ uint4 As[2][4][64];
    __shared__ uint4 Bs[2][4][64];

    const int t  = threadIdx.x;
    const int tx = t & 15;
    const int ty = t >> 4;
    const int bx = blockIdx.x;      // 0..63   (N/64)
    const int by = blockIdx.y;      // 0..127  (M/64)

    // staging: wave w stages chunk w; lane sl loads row sl (coalesced),
    // writes transposed slot.
    const int sc = t >> 6;
    const int sl = t & 63;
    const uint4* gA = (const uint4*)ap + (size_t)sc * 8192 + (size_t)by * 64 + sl;
    const uint4* gB = (const uint4*)wp + (size_t)sc * 4096 + (size_t)bx * 64 + sl;
    const int slot = (sl & 3) * 16 + (sl >> 2);
    uint4* sA = &As[0][sc][slot];
    uint4* sB = &Bs[0][sc][slot];

    sA[0] = gA[0];
    sB[0] = gB[0];

    int c00 = 0, c01 = 0, c02 = 0, c03 = 0;
    int c10 = 0, c11 = 0, c12 = 0, c13 = 0;
    int c20 = 0, c21 = 0, c22 = 0, c23 = 0;
    int c30 = 0, c31 = 0, c32 = 0, c33 = 0;

    __syncthreads();

    for (int k = 0; k < 8; ++k) {
        const int buf = k & 1;
        uint4 rA, rB;
        if (k < 7) {
            rA = gA[(size_t)(k + 1) * 32768];   // 4 chunks * 8192
            rB = gB[(size_t)(k + 1) * 16384];   // 4 chunks * 4096
        }

        CSTEP(0)
        CSTEP(1)
        CSTEP(2)
        CSTEP(3)

        if (k < 7) {
            sA[(buf ^ 1) * 256] = rA;
            sB[(buf ^ 1) * 256] = rB;
        }
        __syncthreads();
    }

    // Epilogue: BN (left-assoc, no FMA contraction) + binarize + bit-pack.
    {
#pragma clang fp contract(off)
        const int col0 = bx * 64 + tx * 4;
        const float4 mn = *(const float4*)(mean + col0);
        const float4 rv = *(const float4*)(rsq + col0);
        const float4 gm = *(const float4*)(gamma + col0);
        const float4 bt = *(const float4*)(beta + col0);

        const int row0 = by * 64 + ty * 4;
        const int kw   = bx * 2 + (tx >> 3);     // global kword this group builds
        const int chnk = kw >> 2;
        const int pos  = kw & 3;
        const int sh   = (tx & 7) * 4;

        EPIROW(c00, c01, c02, c03, 0)
        EPIROW(c10, c11, c12, c13, 1)
        EPIROW(c20, c21, c22, c23, 2)
        EPIROW(c30, c31, c32, c33, 3)
    }
}

// ---------------------------------------------------------------------------
// Final 8192x10x4096 binary GEMM + TensorNorm.
// ---------------------------------------------------------------------------
__global__ __launch_bounds__(256) void final_kernel(
    const uint32_t* __restrict__ ap, const uint32_t* __restrict__ wpo,
    const float* __restrict__ tn_m, const float* __restrict__ tn_v,
    const float* __restrict__ tn_w, const float* __restrict__ tn_b,
    float* __restrict__ out)
{
#pragma clang fp contract(off)
    __shared__ uint4 wsh[10][32];
    for (int i = threadIdx.x; i < 320; i += 256)
        ((uint4*)wsh)[i] = ((const uint4*)wpo)[i];
    __syncthreads();

    const int b = blockIdx.x * 256 + threadIdx.x;   // 8192 exact
    const uint4* pa = (const uint4*)ap + b;
    int cnt[10];
#pragma unroll
    for (int o = 0; o < 10; ++o) cnt[o] = 0;

    for (int k = 0; k < 32; ++k) {
        uint4 A = pa[(size_t)k * 8192];
#pragma unroll
        for (int o = 0; o < 10; ++o) {
            uint4 B = wsh[o][k];
            cnt[o] += __popc(A.x ^ B.x) + __popc(A.y ^ B.y)
                    + __popc(A.z ^ B.z) + __popc(A.w ^ B.w);
        }
    }

    const float m  = tn_m[0];
    const float r  = 1.0f / sqrtf(tn_v[0] + 1e-4f);
    const float w  = tn_w[0];
    const float bb = tn_b[0];
#pragma unroll
    for (int o = 0; o < 10; ++o) {
        float d = (float)(4096 - 2 * cnt[o]);
        float t = (d - m) * r;
        out[b * 10 + o] = t * w + bb;
    }
}

// ---------------------------------------------------------------------------
extern "C" void kernel_launch(void* const* d_in, const int* in_sizes, int n_in,
                              void* d_out, int out_size, void* d_ws, size_t ws_size,
                              hipStream_t stream) {
    const float* x     = (const float*)d_in[0];
    const float* W     = (const float*)d_in[1];
    const float* Wout  = (const float*)d_in[2];
    const float* gamma = (const float*)d_in[3];
    const float* beta  = (const float*)d_in[4];
    const float* mean  = (const float*)d_in[5];
    const float* var   = (const float*)d_in[6];
    const float* tn_w  = (const float*)d_in[7];
    const float* tn_b  = (const float*)d_in[8];
    const float* tn_m  = (const float*)d_in[9];
    const float* tn_v  = (const float*)d_in[10];
    float* out = (float*)d_out;

    uint8_t* ws = (uint8_t*)d_ws;
    uint32_t* ap0 = (uint32_t*)(ws);                      // 4 MB [32][8192][4]
    uint32_t* ap1 = (uint32_t*)(ws + (4u << 20));         // 4 MB
    uint32_t* wp  = (uint32_t*)(ws + (8u << 20));         // 6 MB [3][32][4096][4]
    uint32_t* wpo = (uint32_t*)(ws + (14u << 20));        // 5 KB [10][128]
    float*    rs  = (float*)   (ws + (14u << 20) + 8192); // 48 KB [3][4096]

    // pack input: 33,554,432 elems / 1024 per block
    pack_ksign_kernel<<<32768, 256, 0, stream>>>(x, ap0, 0.5f, 13);
    // pack hidden weights: 50,331,648 elems / 1024 per block
    pack_ksign_kernel<<<49152, 256, 0, stream>>>(W, wp, 0.0f, 12);
    pack_rm_kernel<<<160, 256, 0, stream>>>(Wout, wpo);
    rsqrt_kernel<<<48, 256, 0, stream>>>(var, rs);

    dim3 grid(64, 128);   // (N/64, M/64)
    bgemm_kernel<<<grid, 256, 0, stream>>>(ap0, wp,            mean,        rs,
                                           gamma,        beta,        ap1);
    bgemm_kernel<<<grid, 256, 0, stream>>>(ap1, wp + (1u<<19), mean + 4096, rs + 4096,
                                           gamma + 4096, beta + 4096, ap0);
    bgemm_kernel<<<grid, 256, 0, stream>>>(ap0, wp + (2u<<19), mean + 8192, rs + 8192,
                                           gamma + 8192, beta + 8192, ap1);

    final_kernel<<<32, 256, 0, stream>>>(ap1, wpo, tn_m, tn_v, tn_w, tn_b, out);
}

// Round 11
// 1917.335 us; speedup vs baseline: 7.0759x; 4.0612x over previous
//
#include <hip/hip_runtime.h>
#include <hip/hip_bf16.h>
#include <stdint.h>

// Layouts (uint4 = 128 bits of packed sign data):
//   ap  : [32 chunks][8192 rows] uint4   activations, chunk-major
//   wp  : [3][32][4096] uint4            hidden weights
//   wpo : [10][32] uint4                 output weights, row-major

// ---------------------------------------------------------------------------
// Pack f32 -> sign bits, 4 elements per thread, chunk-major output.
// For x: binarize(2v-1) >= 0  <=>  v >= 0.5 (exact).
// ---------------------------------------------------------------------------
__global__ __launch_bounds__(256) void pack_ksign_kernel(
    const float* __restrict__ src, uint32_t* __restrict__ dst,
    float thresh, int rbits)
{
    const int t    = threadIdx.x;
    const int lane = t & 63;
    const int gw   = blockIdx.x * 4 + (t >> 6);     // global wave id
    const size_t base = (size_t)gw * 256;           // 256 elems per wave, same row
    const int gr = gw >> 4;                         // global row (4096 elems/row)
    const int l  = gr >> rbits;                     // matrix index
    const int r  = gr & ((1 << rbits) - 1);         // row within matrix
    const int w0 = (gw & 15) * 8;                   // first kword of this span
#pragma unroll
    for (int j = 0; j < 4; ++j) {
        float v = src[base + j * 64 + lane];
        unsigned long long m = __ballot(v >= thresh);
        if (lane == 0) {
            int w = w0 + 2 * j;                     // even kword
            size_t idx = ((size_t)l << (rbits + 7))
                       + (((size_t)(w >> 2) << rbits) + (size_t)r) * 4
                       + (size_t)(w & 3);
            *(uint2*)(dst + idx) = make_uint2((uint32_t)m, (uint32_t)(m >> 32));
        }
    }
}

// Row-major pack for Wout [10][4096] -> [10][128] words
__global__ __launch_bounds__(256) void pack_rm_kernel(const float* __restrict__ src,
                                                      uint32_t* __restrict__ dst) {
    int tid = blockIdx.x * 256 + threadIdx.x;
    bool pred = src[tid] >= 0.0f;
    unsigned long long m = __ballot(pred);
    if ((threadIdx.x & 63) == 0)
        *(uint2*)(dst + (tid >> 5)) = make_uint2((uint32_t)m, (uint32_t)(m >> 32));
}

__global__ __launch_bounds__(256) void rsqrt_kernel(const float* __restrict__ var,
                                                    float* __restrict__ rs) {
    int tid = blockIdx.x * 256 + threadIdx.x;   // 3*4096 exact
    rs[tid] = 1.0f / sqrtf(var[tid] + 1e-5f);
}

// ---------------------------------------------------------------------------
// Binary GEMM: C[b][o] = 4096 - 2*popc(A[b]^W[o]); fused BN + binarize + pack.
// Block 64x64, 256 threads, 4x4 per thread, K-step = 4 chunks (512 bits),
// 8 iters, double-buffered LDS, 1 barrier/iter.
// NO min-waves clause in launch_bounds: with (256,4) the backend capped the
// kernel at 64 VGPR and spilled its ~90-reg working set to scratch
// (R6: FETCH 4.5GB/WRITE 8.6GB of pure spill traffic). Uncapped, the body
// fits in ~96-128 VGPR with zero scratch (R1 precedent: 208 VGPR, no spill).
// LDS layout transposed-within-tile: row (4q + r) lives at slot (r*16 + q).
// ---------------------------------------------------------------------------
#define XP(C, A, B)                                                          \
    C += __popc((A).x ^ (B).x) + __popc((A).y ^ (B).y) +                     \
         __popc((A).z ^ (B).z) + __popc((A).w ^ (B).w)

// one k-chunk: load 4 A-fragments + 4 B-fragments, 16 accumulate ops
#define CSTEP(cc)                                                            \
    {                                                                        \
        uint4 a0 = As[buf][cc][ 0 + ty], a1 = As[buf][cc][16 + ty];          \
        uint4 a2 = As[buf][cc][32 + ty], a3 = As[buf][cc][48 + ty];          \
        uint4 b0 = Bs[buf][cc][ 0 + tx], b1 = Bs[buf][cc][16 + tx];          \
        uint4 b2 = Bs[buf][cc][32 + tx], b3 = Bs[buf][cc][48 + tx];          \
        XP(c00, a0, b0); XP(c01, a0, b1); XP(c02, a0, b2); XP(c03, a0, b3);  \
        XP(c10, a1, b0); XP(c11, a1, b1); XP(c12, a1, b2); XP(c13, a1, b3);  \
        XP(c20, a2, b0); XP(c21, a2, b1); XP(c22, a2, b2); XP(c23, a2, b3);  \
        XP(c30, a3, b0); XP(c31, a3, b1); XP(c32, a3, b2); XP(c33, a3, b3);  \
    }

// BN + binarize + pack one output row (4 cols) and write if leader lane
#define EPIROW(cr0, cr1, cr2, cr3, rr)                                       \
    {                                                                        \
        uint32_t bits = 0;                                                   \
        float d, tt, y;                                                      \
        d = (float)(4096 - 2 * (cr0)); tt = (d - mn.x) * rv.x;               \
        y = tt * gm.x + bt.x; bits |= (y >= 0.0f) ? 1u : 0u;                 \
        d = (float)(4096 - 2 * (cr1)); tt = (d - mn.y) * rv.y;               \
        y = tt * gm.y + bt.y; bits |= (y >= 0.0f) ? 2u : 0u;                 \
        d = (float)(4096 - 2 * (cr2)); tt = (d - mn.z) * rv.z;               \
        y = tt * gm.z + bt.z; bits |= (y >= 0.0f) ? 4u : 0u;                 \
        d = (float)(4096 - 2 * (cr3)); tt = (d - mn.w) * rv.w;               \
        y = tt * gm.w + bt.w; bits |= (y >= 0.0f) ? 8u : 0u;                 \
        uint32_t v = bits << sh;                                             \
        v |= __shfl_xor(v, 1);                                               \
        v |= __shfl_xor(v, 2);                                               \
        v |= __shfl_xor(v, 4);                                               \
        if ((tx & 7) == 0)                                                   \
            apOut[((size_t)chnk * 8192 + (size_t)(row0 + (rr))) * 4 + pos] = v; \
    }

__global__ __launch_bounds__(256) void bgemm_kernel(
    const uint32_t* __restrict__ ap,     // [32][8192] uint4
    const uint32_t* __restrict__ wp,     // [32][4096] uint4
    const float* __restrict__ mean, const float* __restrict__ rsq,
    const float* __restrict__ gamma, const float* __restrict__ beta,
    uint32_t* __restrict__ apOut)        // [32][8192][4] uint32
{
    __shared__ uint4 As[2][4][64];
    __shared__ uint4 Bs[2][4][64];

    const int t  = threadIdx.x;
    const int tx = t & 15;
    const int ty = t >> 4;
    const int bx = blockIdx.x;      // 0..63   (N/64)
    const int by = blockIdx.y;      // 0..127  (M/64)

    // staging: wave w stages chunk w; lane sl loads row sl (coalesced),
    // writes transposed slot.
    const int sc = t >> 6;
    const int sl = t & 63;
    const uint4* gA = (const uint4*)ap + (size_t)sc * 8192 + (size_t)by * 64 + sl;
    const uint4* gB = (const uint4*)wp + (size_t)sc * 4096 + (size_t)bx * 64 + sl;
    const int slot = (sl & 3) * 16 + (sl >> 2);
    uint4* sA = &As[0][sc][slot];
    uint4* sB = &Bs[0][sc][slot];

    sA[0] = gA[0];
    sB[0] = gB[0];

    int c00 = 0, c01 = 0, c02 = 0, c03 = 0;
    int c10 = 0, c11 = 0, c12 = 0, c13 = 0;
    int c20 = 0, c21 = 0, c22 = 0, c23 = 0;
    int c30 = 0, c31 = 0, c32 = 0, c33 = 0;

    __syncthreads();

#pragma unroll 2
    for (int k = 0; k < 8; ++k) {
        const int buf = k & 1;
        uint4 rA, rB;
        if (k < 7) {
            rA = gA[(size_t)(k + 1) * 32768];   // 4 chunks * 8192
            rB = gB[(size_t)(k + 1) * 16384];   // 4 chunks * 4096
        }

        CSTEP(0)
        CSTEP(1)
        CSTEP(2)
        CSTEP(3)

        if (k < 7) {
            sA[(buf ^ 1) * 256] = rA;
            sB[(buf ^ 1) * 256] = rB;
        }
        __syncthreads();
    }

    // Epilogue: BN (left-assoc, no FMA contraction) + binarize + bit-pack.
    {
#pragma clang fp contract(off)
        const int col0 = bx * 64 + tx * 4;
        const float4 mn = *(const float4*)(mean + col0);
        const float4 rv = *(const float4*)(rsq + col0);
        const float4 gm = *(const float4*)(gamma + col0);
        const float4 bt = *(const float4*)(beta + col0);

        const int row0 = by * 64 + ty * 4;
        const int kw   = bx * 2 + (tx >> 3);     // global kword this group builds
        const int chnk = kw >> 2;
        const int pos  = kw & 3;
        const int sh   = (tx & 7) * 4;

        EPIROW(c00, c01, c02, c03, 0)
        EPIROW(c10, c11, c12, c13, 1)
        EPIROW(c20, c21, c22, c23, 2)
        EPIROW(c30, c31, c32, c33, 3)
    }
}

// ---------------------------------------------------------------------------
// Final 8192x10x4096 binary GEMM + TensorNorm.
// ---------------------------------------------------------------------------
__global__ __launch_bounds__(256) void final_kernel(
    const uint32_t* __restrict__ ap, const uint32_t* __restrict__ wpo,
    const float* __restrict__ tn_m, const float* __restrict__ tn_v,
    const float* __restrict__ tn_w, const float* __restrict__ tn_b,
    float* __restrict__ out)
{
#pragma clang fp contract(off)
    __shared__ uint4 wsh[10][32];
    for (int i = threadIdx.x; i < 320; i += 256)
        ((uint4*)wsh)[i] = ((const uint4*)wpo)[i];
    __syncthreads();

    const int b = blockIdx.x * 256 + threadIdx.x;   // 8192 exact
    const uint4* pa = (const uint4*)ap + b;
    int cnt[10];
#pragma unroll
    for (int o = 0; o < 10; ++o) cnt[o] = 0;

    for (int k = 0; k < 32; ++k) {
        uint4 A = pa[(size_t)k * 8192];
#pragma unroll
        for (int o = 0; o < 10; ++o) {
            uint4 B = wsh[o][k];
            cnt[o] += __popc(A.x ^ B.x) + __popc(A.y ^ B.y)
                    + __popc(A.z ^ B.z) + __popc(A.w ^ B.w);
        }
    }

    const float m  = tn_m[0];
    const float r  = 1.0f / sqrtf(tn_v[0] + 1e-4f);
    const float w  = tn_w[0];
    const float bb = tn_b[0];
#pragma unroll
    for (int o = 0; o < 10; ++o) {
        float d = (float)(4096 - 2 * cnt[o]);
        float t = (d - m) * r;
        out[b * 10 + o] = t * w + bb;
    }
}

// ---------------------------------------------------------------------------
extern "C" void kernel_launch(void* const* d_in, const int* in_sizes, int n_in,
                              void* d_out, int out_size, void* d_ws, size_t ws_size,
                              hipStream_t stream) {
    const float* x     = (const float*)d_in[0];
    const float* W     = (const float*)d_in[1];
    const float* Wout  = (const float*)d_in[2];
    const float* gamma = (const float*)d_in[3];
    const float* beta  = (const float*)d_in[4];
    const float* mean  = (const float*)d_in[5];
    const float* var   = (const float*)d_in[6];
    const float* tn_w  = (const float*)d_in[7];
    const float* tn_b  = (const float*)d_in[8];
    const float* tn_m  = (const float*)d_in[9];
    const float* tn_v  = (const float*)d_in[10];
    float* out = (float*)d_out;

    uint8_t* ws = (uint8_t*)d_ws;
    uint32_t* ap0 = (uint32_t*)(ws);                      // 4 MB [32][8192][4]
    uint32_t* ap1 = (uint32_t*)(ws + (4u << 20));         // 4 MB
    uint32_t* wp  = (uint32_t*)(ws + (8u << 20));         // 6 MB [3][32][4096][4]
    uint32_t* wpo = (uint32_t*)(ws + (14u << 20));        // 5 KB [10][128]
    float*    rs  = (float*)   (ws + (14u << 20) + 8192); // 48 KB [3][4096]

    // pack input: 33,554,432 elems / 1024 per block
    pack_ksign_kernel<<<32768, 256, 0, stream>>>(x, ap0, 0.5f, 13);
    // pack hidden weights: 50,331,648 elems / 1024 per block
    pack_ksign_kernel<<<49152, 256, 0, stream>>>(W, wp, 0.0f, 12);
    pack_rm_kernel<<<160, 256, 0, stream>>>(Wout, wpo);
    rsqrt_kernel<<<48, 256, 0, stream>>>(var, rs);

    dim3 grid(64, 128);   // (N/64, M/64)
    bgemm_kernel<<<grid, 256, 0, stream>>>(ap0, wp,            mean,        rs,
                                           gamma,        beta,        ap1);
    bgemm_kernel<<<grid, 256, 0, stream>>>(ap1, wp + (1u<<19), mean + 4096, rs + 4096,
                                           gamma + 4096, beta + 4096, ap0);
    bgemm_kernel<<<grid, 256, 0, stream>>>(ap0, wp + (2u<<19), mean + 8192, rs + 8192,
                                           gamma + 8192, beta + 8192, ap1);

    final_kernel<<<32, 256, 0, stream>>>(ap1, wpo, tn_m, tn_v, tn_w, tn_b, out);
}